// Round 3
// baseline (47.743 us; speedup 1.0000x reference)
//
#include <hip/hip_runtime.h>
#include <stdint.h>

#define NB 200000
#define BB 4
#define GG 64
#define MAXPOS 128
#define BATCH 256
#define KPT 4                      // anchors per thread in K1
#define CH 1024                    // anchors per chunk (= K1 block coverage)
#define NCH ((NB + CH - 1) / CH)   // 196

// ---------------- K0: expand gt to (x1,y1,x2,y2,area,pad,pad,pad) ----------------
__global__ void rpn_prep_kernel(const float* __restrict__ gt, float* __restrict__ gtx) {
    int t = blockIdx.x * blockDim.x + threadIdx.x;
    if (t < BB * GG) {
        float4 g4 = ((const float4*)gt)[t];
        float* o = gtx + t * 8;
        o[0] = g4.x; o[1] = g4.y; o[2] = g4.z; o[3] = g4.w;
        o[4] = (g4.z - g4.x) * (g4.w - g4.y);
        o[5] = 0.0f; o[6] = 0.0f; o[7] = 0.0f;
    }
}

// ---------------- K1: per-anchor threshold flags + per-chunk counts ----------------
// No argmax here: only p = (max_iou >= 0.7), n = (max_iou < 0.3), via
// max_g(inter - t*u) sign tests (two independent fma+max chains).
__global__ __launch_bounds__(256) void rpn_flags_kernel(
        const float* __restrict__ anchors, const float* __restrict__ gtx,
        uint8_t* __restrict__ flags, uint32_t* __restrict__ chunkCnt) {
    int b = blockIdx.y;
    int tid = threadIdx.x, lane = tid & 63, wid = tid >> 6;
    int base = blockIdx.x * CH + tid;          // anchor for k=0; k strides by 256
    const float* __restrict__ G = gtx + b * GG * 8;   // uniform -> s_load

    float4 a[KPT];
    float a1[KPT], mp[KPT], mn[KPT];
    #pragma unroll
    for (int k = 0; k < KPT; ++k) {
        int i = base + k * 256;
        a[k] = (i < NB) ? ((const float4*)anchors)[(size_t)b * NB + i]
                        : make_float4(0.f, 0.f, 0.f, 0.f);
        a1[k] = (a[k].z - a[k].x) * (a[k].w - a[k].y);
        mp[k] = -1.0f; mn[k] = -1.0f;
    }

    #pragma unroll 8
    for (int g = 0; g < GG; ++g) {
        float gx1 = G[g * 8 + 0], gy1 = G[g * 8 + 1];
        float gx2 = G[g * 8 + 2], gy2 = G[g * 8 + 3];
        float ga  = G[g * 8 + 4];
        #pragma unroll
        for (int k = 0; k < KPT; ++k) {
            float w = fminf(a[k].z, gx2) - fmaxf(a[k].x, gx1);
            float h = fminf(a[k].w, gy2) - fmaxf(a[k].y, gy1);
            w = fmaxf(w, 0.0f); h = fmaxf(h, 0.0f);
            float inter = w * h;
            float u = (a1[k] + ga) - inter;               // union > 0
            mp[k] = fmaxf(mp[k], __builtin_fmaf(-0.7f, u, inter));
            mn[k] = fmaxf(mn[k], __builtin_fmaf(-0.3f, u, inter));
        }
    }

    uint32_t pn = 0;
    #pragma unroll
    for (int k = 0; k < KPT; ++k) {
        int i = base + k * 256;
        bool valid = i < NB;
        bool p = valid && (mp[k] >= 0.0f);
        bool n = valid && (mn[k] < 0.0f);
        if (valid) flags[(size_t)b * NB + i] = (uint8_t)((p ? 1 : 0) | (n ? 2 : 0));
        pn += (p ? 1u : 0u) + (n ? 0x10000u : 0u);
    }
    // block-wide count (pos low16, neg high16)
    for (int off = 32; off > 0; off >>= 1) pn += __shfl_down(pn, off);
    __shared__ uint32_t wSum[4];
    if (lane == 0) wSum[wid] = pn;
    __syncthreads();
    if (tid == 0)
        chunkCnt[b * NCH + blockIdx.x] = wSum[0] + wSum[1] + wSum[2] + wSum[3];
}

// ---------------- K2: scan chunk counts, parallel ordered selection, loss ----------------
__global__ __launch_bounds__(1024) void rpn_select_kernel(
        const uint8_t* __restrict__ flags,
        const float* __restrict__ logits, const float* __restrict__ breg,
        const float* __restrict__ anchors, const float* __restrict__ gt,
        const float* __restrict__ gtx,
        const uint32_t* __restrict__ chunkCnt,
        float* __restrict__ partial) {
    int b = blockIdx.x;
    const uint8_t* __restrict__ F = flags + (size_t)b * NB;
    const float* __restrict__ G = gtx + b * GG * 8;
    __shared__ int basP[NCH], basN[NCH];
    __shared__ unsigned long long wTot[16];
    __shared__ int sNumPos, sNumNeg;
    __shared__ int selPos[MAXPOS];
    __shared__ int selNeg[BATCH];
    __shared__ float sB, sS;
    int tid = threadIdx.x, lane = tid & 63, wid = tid >> 6;

    // --- block-wide exclusive scan of packed (pos, neg) chunk counts ---
    unsigned long long e = 0ULL;
    if (tid < NCH) {
        uint32_t c = chunkCnt[b * NCH + tid];
        e = (unsigned long long)(c & 0xFFFFu) | ((unsigned long long)(c >> 16) << 32);
    }
    unsigned long long inc = e;
    for (int off = 1; off < 64; off <<= 1) {
        unsigned long long v = __shfl_up(inc, off);
        if (lane >= off) inc += v;
    }
    if (lane == 63) wTot[wid] = inc;
    if (tid == 0) { sB = 0.0f; sS = 0.0f; }
    __syncthreads();
    if (wid == 0) {
        unsigned long long w = (lane < 16) ? wTot[lane] : 0ULL;
        unsigned long long winc = w;
        for (int off = 1; off < 16; off <<= 1) {
            unsigned long long v = __shfl_up(winc, off);
            if (lane >= off) winc += v;
        }
        if (lane < 16) wTot[lane] = winc - w;     // exclusive base per wave
        if (lane == 15) {
            int tp = (int)(winc & 0xFFFFFFFFULL);
            int tn = (int)(winc >> 32);
            int np_ = min(tp, MAXPOS);
            sNumPos = np_;
            sNumNeg = min(tn, BATCH - np_);
        }
    }
    __syncthreads();
    if (tid < NCH) {
        unsigned long long ex = wTot[wid] + (inc - e);
        basP[tid] = (int)(ex & 0xFFFFFFFFULL);
        basN[tid] = (int)(ex >> 32);
    }
    __syncthreads();
    int numPos = sNumPos, numNeg = sNumNeg;

    // --- parallel ordered selection: wave w handles chunks w, w+16, ... ---
    for (int c = wid; c < NCH; c += 16) {
        int bp = basP[c], bn = basN[c];
        if (bp >= numPos && bn >= numNeg) break;  // bases monotone, wave-uniform
        int offP = 0, offN = 0;
        #pragma unroll
        for (int s = 0; s < CH / 64; ++s) {
            int idx = c * CH + s * 64 + lane;
            uint8_t f = (idx < NB) ? F[idx] : (uint8_t)0;
            bool p = (f & 1) != 0, n = (f & 2) != 0;
            unsigned long long mpm = __ballot(p), mnm = __ballot(n);
            unsigned long long lt = (1ULL << lane) - 1ULL;
            int rp = bp + offP + __popcll(mpm & lt);
            int rn = bn + offN + __popcll(mnm & lt);
            if (p && rp < numPos) selPos[rp] = idx;
            if (n && rn < numNeg) selNeg[rn] = idx;
            offP += __popcll(mpm); offN += __popcll(mnm);
        }
    }
    __syncthreads();

    // --- losses over selected samples ---
    float bce_acc = 0.0f, sl1_acc = 0.0f;
    for (int t = tid; t < numPos; t += 1024) {
        int i = selPos[t];
        float x = logits[(size_t)b * NB + i];
        bce_acc += fmaxf(x, 0.0f) - x + log1pf(expf(-fabsf(x)));
        float4 a = ((const float4*)anchors)[(size_t)b * NB + i];
        float a1 = (a.z - a.x) * (a.w - a.y);
        // recompute argmax over gts (cross-mult, first-max) for this positive
        float ib = -1.0f, ub = 1.0f;
        int bi = 0;
        #pragma unroll 8
        for (int g = 0; g < GG; ++g) {
            float gx1 = G[g * 8 + 0], gy1 = G[g * 8 + 1];
            float gx2 = G[g * 8 + 2], gy2 = G[g * 8 + 3];
            float ga  = G[g * 8 + 4];
            float w = fminf(a.z, gx2) - fmaxf(a.x, gx1);
            float h = fminf(a.w, gy2) - fmaxf(a.y, gy1);
            w = fmaxf(w, 0.0f); h = fmaxf(h, 0.0f);
            float inter = w * h;
            float u = (a1 + ga) - inter;
            bool better = inter * ub > ib * u;
            ib = better ? inter : ib;
            ub = better ? u : ub;
            bi = better ? g : bi;
        }
        const float* t4 = gt + (size_t)(b * GG + bi) * 4;
        float tx1 = t4[0], ty1 = t4[1], tx2 = t4[2], ty2 = t4[3];
        float acx = (a.x + a.z) / 2.0f, acy = (a.y + a.w) / 2.0f;
        float aw = a.z - a.x, ah = a.w - a.y;
        float tcx = (tx1 + tx2) / 2.0f, tcy = (ty1 + ty2) / 2.0f;
        float tw = tx2 - tx1, th = ty2 - ty1;
        float d0 = (tcx - acx) / aw;
        float d1 = (tcy - acy) / ah;
        float d2 = logf(tw / aw);
        float d3 = logf(th / ah);
        float4 r = ((const float4*)breg)[(size_t)b * NB + i];
        float df;
        df = fabsf(r.x - d0); sl1_acc += (df < 1.0f) ? 0.5f * df * df : df - 0.5f;
        df = fabsf(r.y - d1); sl1_acc += (df < 1.0f) ? 0.5f * df * df : df - 0.5f;
        df = fabsf(r.z - d2); sl1_acc += (df < 1.0f) ? 0.5f * df * df : df - 0.5f;
        df = fabsf(r.w - d3); sl1_acc += (df < 1.0f) ? 0.5f * df * df : df - 0.5f;
    }
    for (int t = tid; t < numNeg; t += 1024) {
        int i = selNeg[t];
        float x = logits[(size_t)b * NB + i];
        bce_acc += fmaxf(x, 0.0f) + log1pf(expf(-fabsf(x)));
    }
    for (int off = 32; off > 0; off >>= 1) {
        bce_acc += __shfl_down(bce_acc, off);
        sl1_acc += __shfl_down(sl1_acc, off);
    }
    if (lane == 0) {
        atomicAdd(&sB, bce_acc);
        atomicAdd(&sS, sl1_acc);
    }
    __syncthreads();
    if (tid == 0) {
        partial[b * 4 + 0] = sB;
        partial[b * 4 + 1] = (float)(numPos + numNeg);
        partial[b * 4 + 2] = sS;
        partial[b * 4 + 3] = (float)numPos;
    }
}

// ---------------- K3: finalize ----------------
__global__ void rpn_finalize_kernel(const float* __restrict__ partial, float* __restrict__ out) {
    float bce = 0.0f, val = 0.0f, sl1 = 0.0f, np = 0.0f;
    for (int b = 0; b < BB; ++b) {
        bce += partial[b * 4 + 0];
        val += partial[b * 4 + 1];
        sl1 += partial[b * 4 + 2];
        np  += partial[b * 4 + 3];
    }
    out[0] = bce / fmaxf(val, 1.0f);
    out[1] = sl1 / fmaxf(np * 4.0f, 1.0f);
}

extern "C" void kernel_launch(void* const* d_in, const int* in_sizes, int n_in,
                              void* d_out, int out_size, void* d_ws, size_t ws_size,
                              hipStream_t stream) {
    const float* cls  = (const float*)d_in[0];  // [B,N,1]
    const float* breg = (const float*)d_in[1];  // [B,N,4]
    const float* anch = (const float*)d_in[2];  // [B,N,4]
    const float* gt   = (const float*)d_in[3];  // [B,G,4]
    float* out = (float*)d_out;

    float*    gtx      = (float*)d_ws;                                   // 8 KB
    uint8_t*  flags    = (uint8_t*)d_ws + 8192;                          // B*N
    uint32_t* chunkCnt = (uint32_t*)((uint8_t*)d_ws + 8192 + 800000);    // B*NCH
    float*    partial  = (float*)((uint8_t*)d_ws + 8192 + 800000 + BB * NCH * 4);

    rpn_prep_kernel<<<1, 256, 0, stream>>>(gt, gtx);
    dim3 g1(NCH, BB);
    rpn_flags_kernel<<<g1, 256, 0, stream>>>(anch, gtx, flags, chunkCnt);
    rpn_select_kernel<<<BB, 1024, 0, stream>>>(flags, cls, breg, anch, gt, gtx,
                                               chunkCnt, partial);
    rpn_finalize_kernel<<<1, 1, 0, stream>>>(partial, out);
}

// Round 4
// 39.973 us; speedup vs baseline: 1.1944x; 1.1944x over previous
//
#include <hip/hip_runtime.h>
#include <stdint.h>

#define NB 200000
#define BB 4
#define GG 64
#define MAXPOS 128
#define BATCH 256
#define KPT 2                      // anchors per thread in K1
#define CH 512                     // anchors per K1 block (256 thr * KPT)
#define NCH ((NB + CH - 1) / CH)   // 391

// ---------------- K1: per-anchor threshold flags + per-chunk counts ----------------
// GT boxes live in LDS as 8-float records (x1,y1,x2,y2,area,pad*3).
// Per g: one ds_read_b128 (coords) + one ds_read_b32 (area), literal offsets,
// uniform address -> broadcast. Body: two fma+max sign tests, no argmax.
__global__ __launch_bounds__(256) void rpn_flags_kernel(
        const float* __restrict__ anchors, const float* __restrict__ gt,
        uint8_t* __restrict__ flags, uint32_t* __restrict__ chunkCnt) {
    int b = blockIdx.y;
    int tid = threadIdx.x, lane = tid & 63, wid = tid >> 6;
    __shared__ __align__(16) float sG[GG * 8];
    if (tid < GG) {
        float4 g4 = ((const float4*)gt)[b * GG + tid];
        float* o = sG + tid * 8;
        o[0] = g4.x; o[1] = g4.y; o[2] = g4.z; o[3] = g4.w;
        o[4] = (g4.z - g4.x) * (g4.w - g4.y);
    }
    __syncthreads();

    int base = blockIdx.x * CH + tid;          // anchor for k=0; k strides by 256
    float4 a[KPT];
    float a1[KPT], mp[KPT], mn[KPT];
    #pragma unroll
    for (int k = 0; k < KPT; ++k) {
        int i = base + k * 256;
        a[k] = (i < NB) ? ((const float4*)anchors)[(size_t)b * NB + i]
                        : make_float4(0.f, 0.f, 0.f, 0.f);
        a1[k] = (a[k].z - a[k].x) * (a[k].w - a[k].y);
        mp[k] = -1.0f; mn[k] = -1.0f;
    }

    #pragma unroll 8
    for (int g = 0; g < GG; ++g) {
        float4 c = *(const float4*)(sG + g * 8);   // ds_read_b128 offset:g*32
        float ga = sG[g * 8 + 4];                  // ds_read_b32  offset:g*32+16
        #pragma unroll
        for (int k = 0; k < KPT; ++k) {
            float w = fminf(a[k].z, c.z) - fmaxf(a[k].x, c.x);
            float h = fminf(a[k].w, c.w) - fmaxf(a[k].y, c.y);
            w = fmaxf(w, 0.0f); h = fmaxf(h, 0.0f);
            float inter = w * h;
            float u = (a1[k] + ga) - inter;               // union > 0
            mp[k] = fmaxf(mp[k], __builtin_fmaf(-0.7f, u, inter));
            mn[k] = fmaxf(mn[k], __builtin_fmaf(-0.3f, u, inter));
        }
    }

    uint32_t pn = 0;
    #pragma unroll
    for (int k = 0; k < KPT; ++k) {
        int i = base + k * 256;
        bool valid = i < NB;
        bool p = valid && (mp[k] >= 0.0f);
        bool n = valid && (mn[k] < 0.0f);
        if (valid) flags[(size_t)b * NB + i] = (uint8_t)((p ? 1 : 0) | (n ? 2 : 0));
        pn += (p ? 1u : 0u) + (n ? 0x10000u : 0u);
    }
    // block-wide count (pos low16, neg high16)
    for (int off = 32; off > 0; off >>= 1) pn += __shfl_down(pn, off);
    __shared__ uint32_t wSum[4];
    if (lane == 0) wSum[wid] = pn;
    __syncthreads();
    if (tid == 0)
        chunkCnt[b * NCH + blockIdx.x] = wSum[0] + wSum[1] + wSum[2] + wSum[3];
}

// ---------------- K2: scan chunk counts, parallel ordered selection, loss ----------------
__global__ __launch_bounds__(1024) void rpn_select_kernel(
        const uint8_t* __restrict__ flags,
        const float* __restrict__ logits, const float* __restrict__ breg,
        const float* __restrict__ anchors, const float* __restrict__ gt,
        const uint32_t* __restrict__ chunkCnt,
        float* __restrict__ partial) {
    int b = blockIdx.x;
    const uint8_t* __restrict__ F = flags + (size_t)b * NB;
    __shared__ __align__(16) float sG[GG * 8];
    __shared__ int basP[NCH], basN[NCH];
    __shared__ unsigned long long wTot[16];
    __shared__ int sNumPos, sNumNeg;
    __shared__ int selPos[MAXPOS];
    __shared__ int selNeg[BATCH];
    __shared__ float sB, sS;
    int tid = threadIdx.x, lane = tid & 63, wid = tid >> 6;

    if (tid < GG) {
        float4 g4 = ((const float4*)gt)[b * GG + tid];
        float* o = sG + tid * 8;
        o[0] = g4.x; o[1] = g4.y; o[2] = g4.z; o[3] = g4.w;
        o[4] = (g4.z - g4.x) * (g4.w - g4.y);
    }

    // --- block-wide exclusive scan of packed (pos, neg) chunk counts ---
    unsigned long long e = 0ULL;
    if (tid < NCH) {
        uint32_t c = chunkCnt[b * NCH + tid];
        e = (unsigned long long)(c & 0xFFFFu) | ((unsigned long long)(c >> 16) << 32);
    }
    unsigned long long inc = e;
    for (int off = 1; off < 64; off <<= 1) {
        unsigned long long v = __shfl_up(inc, off);
        if (lane >= off) inc += v;
    }
    if (lane == 63) wTot[wid] = inc;
    if (tid == 0) { sB = 0.0f; sS = 0.0f; }
    __syncthreads();
    if (wid == 0) {
        unsigned long long w = (lane < 16) ? wTot[lane] : 0ULL;
        unsigned long long winc = w;
        for (int off = 1; off < 16; off <<= 1) {
            unsigned long long v = __shfl_up(winc, off);
            if (lane >= off) winc += v;
        }
        if (lane < 16) wTot[lane] = winc - w;     // exclusive base per wave
        if (lane == 15) {
            int tp = (int)(winc & 0xFFFFFFFFULL);
            int tn = (int)(winc >> 32);
            int np_ = min(tp, MAXPOS);
            sNumPos = np_;
            sNumNeg = min(tn, BATCH - np_);
        }
    }
    __syncthreads();
    if (tid < NCH) {
        unsigned long long ex = wTot[wid] + (inc - e);
        basP[tid] = (int)(ex & 0xFFFFFFFFULL);
        basN[tid] = (int)(ex >> 32);
    }
    __syncthreads();
    int numPos = sNumPos, numNeg = sNumNeg;

    // --- parallel ordered selection: wave w handles chunks w, w+16, ... ---
    for (int c = wid; c < NCH; c += 16) {
        int bp = basP[c], bn = basN[c];
        if (bp >= numPos && bn >= numNeg) break;  // bases monotone, wave-uniform
        int offP = 0, offN = 0;
        #pragma unroll
        for (int s = 0; s < CH / 64; ++s) {
            int idx = c * CH + s * 64 + lane;
            uint8_t f = (idx < NB) ? F[idx] : (uint8_t)0;
            bool p = (f & 1) != 0, n = (f & 2) != 0;
            unsigned long long mpm = __ballot(p), mnm = __ballot(n);
            unsigned long long lt = (1ULL << lane) - 1ULL;
            int rp = bp + offP + __popcll(mpm & lt);
            int rn = bn + offN + __popcll(mnm & lt);
            if (p && rp < numPos) selPos[rp] = idx;
            if (n && rn < numNeg) selNeg[rn] = idx;
            offP += __popcll(mpm); offN += __popcll(mnm);
        }
    }
    __syncthreads();

    // --- losses over selected samples ---
    float bce_acc = 0.0f, sl1_acc = 0.0f;
    for (int t = tid; t < numPos; t += 1024) {
        int i = selPos[t];
        float x = logits[(size_t)b * NB + i];
        bce_acc += fmaxf(x, 0.0f) - x + log1pf(expf(-fabsf(x)));
        float4 a = ((const float4*)anchors)[(size_t)b * NB + i];
        float a1 = (a.z - a.x) * (a.w - a.y);
        // recompute argmax over gts (cross-mult, first-max) for this positive
        float ib = -1.0f, ub = 1.0f;
        int bi = 0;
        #pragma unroll 8
        for (int g = 0; g < GG; ++g) {
            float4 c = *(const float4*)(sG + g * 8);
            float ga = sG[g * 8 + 4];
            float w = fminf(a.z, c.z) - fmaxf(a.x, c.x);
            float h = fminf(a.w, c.w) - fmaxf(a.y, c.y);
            w = fmaxf(w, 0.0f); h = fmaxf(h, 0.0f);
            float inter = w * h;
            float u = (a1 + ga) - inter;
            bool better = inter * ub > ib * u;
            ib = better ? inter : ib;
            ub = better ? u : ub;
            bi = better ? g : bi;
        }
        const float* t4 = sG + bi * 8;
        float tx1 = t4[0], ty1 = t4[1], tx2 = t4[2], ty2 = t4[3];
        float acx = (a.x + a.z) / 2.0f, acy = (a.y + a.w) / 2.0f;
        float aw = a.z - a.x, ah = a.w - a.y;
        float tcx = (tx1 + tx2) / 2.0f, tcy = (ty1 + ty2) / 2.0f;
        float tw = tx2 - tx1, th = ty2 - ty1;
        float d0 = (tcx - acx) / aw;
        float d1 = (tcy - acy) / ah;
        float d2 = logf(tw / aw);
        float d3 = logf(th / ah);
        float4 r = ((const float4*)breg)[(size_t)b * NB + i];
        float df;
        df = fabsf(r.x - d0); sl1_acc += (df < 1.0f) ? 0.5f * df * df : df - 0.5f;
        df = fabsf(r.y - d1); sl1_acc += (df < 1.0f) ? 0.5f * df * df : df - 0.5f;
        df = fabsf(r.z - d2); sl1_acc += (df < 1.0f) ? 0.5f * df * df : df - 0.5f;
        df = fabsf(r.w - d3); sl1_acc += (df < 1.0f) ? 0.5f * df * df : df - 0.5f;
    }
    for (int t = tid; t < numNeg; t += 1024) {
        int i = selNeg[t];
        float x = logits[(size_t)b * NB + i];
        bce_acc += fmaxf(x, 0.0f) + log1pf(expf(-fabsf(x)));
    }
    for (int off = 32; off > 0; off >>= 1) {
        bce_acc += __shfl_down(bce_acc, off);
        sl1_acc += __shfl_down(sl1_acc, off);
    }
    if (lane == 0) {
        atomicAdd(&sB, bce_acc);
        atomicAdd(&sS, sl1_acc);
    }
    __syncthreads();
    if (tid == 0) {
        partial[b * 4 + 0] = sB;
        partial[b * 4 + 1] = (float)(numPos + numNeg);
        partial[b * 4 + 2] = sS;
        partial[b * 4 + 3] = (float)numPos;
    }
}

// ---------------- K3: finalize ----------------
__global__ void rpn_finalize_kernel(const float* __restrict__ partial, float* __restrict__ out) {
    float bce = 0.0f, val = 0.0f, sl1 = 0.0f, np = 0.0f;
    for (int b = 0; b < BB; ++b) {
        bce += partial[b * 4 + 0];
        val += partial[b * 4 + 1];
        sl1 += partial[b * 4 + 2];
        np  += partial[b * 4 + 3];
    }
    out[0] = bce / fmaxf(val, 1.0f);
    out[1] = sl1 / fmaxf(np * 4.0f, 1.0f);
}

extern "C" void kernel_launch(void* const* d_in, const int* in_sizes, int n_in,
                              void* d_out, int out_size, void* d_ws, size_t ws_size,
                              hipStream_t stream) {
    const float* cls  = (const float*)d_in[0];  // [B,N,1]
    const float* breg = (const float*)d_in[1];  // [B,N,4]
    const float* anch = (const float*)d_in[2];  // [B,N,4]
    const float* gt   = (const float*)d_in[3];  // [B,G,4]
    float* out = (float*)d_out;

    uint8_t*  flags    = (uint8_t*)d_ws;                            // B*N
    uint32_t* chunkCnt = (uint32_t*)((uint8_t*)d_ws + 800000);      // B*NCH
    float*    partial  = (float*)((uint8_t*)d_ws + 800000 + BB * NCH * 4);

    dim3 g1(NCH, BB);
    rpn_flags_kernel<<<g1, 256, 0, stream>>>(anch, gt, flags, chunkCnt);
    rpn_select_kernel<<<BB, 1024, 0, stream>>>(flags, cls, breg, anch, gt,
                                               chunkCnt, partial);
    rpn_finalize_kernel<<<1, 1, 0, stream>>>(partial, out);
}